// Round 1
// baseline (952.518 us; speedup 1.0000x reference)
//
#include <hip/hip_runtime.h>
#include <hip/hip_bf16.h>
#include <math.h>

// ---------------- problem constants ----------------
#define D_MODEL 1024
#define N_EXP   8
#define D_FF    4096
#define T_TOK   8192
#define NPAIR   (T_TOK * 2)              // 16384 token-expert pairs (top-2)
#define CAP_ROWS (NPAIR + N_EXP * 128)   // 17408: worst-case padded rows (128-granular)
#define MAX_T256 72                      // worst-case 256-row M-tiles: (17408+8*128)/256
#define BKB 128                          // bytes per k-row of a K-tile (64 bf16)

typedef __attribute__((ext_vector_type(4)))  float  f32x4;
typedef __attribute__((ext_vector_type(16))) float  f32x16;
typedef __attribute__((ext_vector_type(8)))  __bf16 bf16x8;
typedef __attribute__((ext_vector_type(4)))  __bf16 bf16x4;

// ---------------- workspace layout (bytes) — unchanged footprint ----------------
#define OFF_W1T   0
#define OFF_W2T   67108864
#define OFF_H     134217728
#define OFF_XR    276824064
#define OFF_META  312475648
#define M_PAIREXP 0         // int[16384]
#define M_PAIRW   65536     // float[16384]
#define M_ROW2P   131072    // int[17408]
#define M_COUNTS  200704    // int[8]
#define M_PADST   200736    // int[8]
#define M_CURSOR  200768    // int[8*32]
#define M_T2E     201792    // int[<=136] (72 used)
#define M_TROW    202336    // int[<=136] (72 used)
#define M_TLIM    202880    // int[72]  (rows valid in this 256-tile: 128 or 256)

__device__ __forceinline__ void async_copy16(const void* g, void* s) {
  __builtin_amdgcn_global_load_lds(
      (const __attribute__((address_space(1))) void*)g,
      (__attribute__((address_space(3))) void*)s, 16, 0, 0);
}

// barrier that is also a compiler memory fence (no extra instructions):
// pins ds_read/global ops inside their phase; s_barrier alone is not a
// codegen fence for loads.
__device__ __forceinline__ void wg_barrier() {
  asm volatile("" ::: "memory");
  __builtin_amdgcn_s_barrier();
  asm volatile("" ::: "memory");
}

// tanh-form gelu via sigmoid: gelu(v) = v * sigmoid(1.595769*(v + 0.044715 v^3))
__device__ __forceinline__ float gelu_fast(float v) {
  float u = 1.5957691216057308f * (v + 0.044715f * v * v * v);
  return v * __builtin_amdgcn_rcpf(1.f + __expf(-u));
}

// ---------------- gating: logits, softmax, top-2 ----------------
__global__ void k_gate(const float* __restrict__ x, const float* __restrict__ Wg,
                       const float* __restrict__ bg, float* __restrict__ logits_out,
                       int* __restrict__ pairExpert, float* __restrict__ pairW) {
  const int t    = blockIdx.x * 4 + (threadIdx.x >> 6);
  const int lane = threadIdx.x & 63;
  const float* xp = x + (size_t)t * D_MODEL;
  float acc[8];
#pragma unroll
  for (int e = 0; e < 8; e++) acc[e] = 0.f;
#pragma unroll
  for (int i = 0; i < 16; i++) {
    int d = i * 64 + lane;
    float xv = xp[d];
    const float4* wr = (const float4*)(Wg + d * 8);
    float4 w0 = wr[0], w1 = wr[1];
    acc[0] += xv * w0.x; acc[1] += xv * w0.y; acc[2] += xv * w0.z; acc[3] += xv * w0.w;
    acc[4] += xv * w1.x; acc[5] += xv * w1.y; acc[6] += xv * w1.z; acc[7] += xv * w1.w;
  }
#pragma unroll
  for (int e = 0; e < 8; e++)
#pragma unroll
    for (int off = 32; off > 0; off >>= 1) acc[e] += __shfl_down(acc[e], off);
  if (lane == 0) {
    float l[8];
#pragma unroll
    for (int e = 0; e < 8; e++) { l[e] = acc[e] + bg[e]; logits_out[t * 8 + e] = l[e]; }
    float m = l[0];
#pragma unroll
    for (int e = 1; e < 8; e++) m = fmaxf(m, l[e]);
    float p[8], s = 0.f;
#pragma unroll
    for (int e = 0; e < 8; e++) { p[e] = expf(l[e] - m); s += p[e]; }
    float inv = 1.0f / s;
    int i1 = 0;
#pragma unroll
    for (int e = 1; e < 8; e++) if (l[e] > l[i1]) i1 = e;
    int i2 = (i1 == 0) ? 1 : 0;
#pragma unroll
    for (int e = 0; e < 8; e++) if (e != i1 && l[e] > l[i2]) i2 = e;
    pairExpert[t * 2 + 0] = i1; pairW[t * 2 + 0] = p[i1] * inv;
    pairExpert[t * 2 + 1] = i2; pairW[t * 2 + 1] = p[i2] * inv;
  }
}

// ---------------- routing metadata ----------------
__global__ void k_init(int* __restrict__ row2pair) {
  int i = blockIdx.x * 256 + threadIdx.x;
  if (i < CAP_ROWS) row2pair[i] = -1;
}

__global__ void k_offsets(const int* __restrict__ pairExpert, int* __restrict__ counts,
                          int* __restrict__ padStart, int* __restrict__ cursor,
                          int* __restrict__ t2e, int* __restrict__ trow,
                          int* __restrict__ tlim) {
  __shared__ int hist[8];
  int tid = threadIdx.x;
  if (tid < 8) hist[tid] = 0;
  __syncthreads();
  for (int i = tid; i < NPAIR; i += 256) atomicAdd(&hist[pairExpert[i]], 1);
  __syncthreads();
  if (tid == 0) {
    int run = 0, nt = 0;
    for (int e = 0; e < 8; e++) {
      counts[e] = hist[e]; padStart[e] = run; cursor[e * 32] = 0;
      int rows = ((hist[e] + 127) >> 7) << 7;   // 128-granular padding (unchanged)
      for (int r0 = 0; r0 < rows; r0 += 256) {  // 256-row M-tiles, tail may be 128
        t2e[nt] = e; trow[nt] = run + r0;
        int rem = rows - r0;
        tlim[nt] = rem < 256 ? rem : 256;
        nt++;
      }
      run += rows;
    }
    for (; nt < MAX_T256; nt++) t2e[nt] = -1;
  }
}

__global__ void k_place(const int* __restrict__ pairExpert, const int* __restrict__ padStart,
                        int* __restrict__ cursor, int* __restrict__ row2pair) {
  int p = blockIdx.x * 256 + threadIdx.x;
  if (p >= NPAIR) return;
  int e = pairExpert[p];
  int r = atomicAdd(&cursor[e * 32], 1);
  row2pair[padStart[e] + r] = p;
}

// ---------------- gather x rows -> routed bf16 ----------------
__global__ void k_gather(const float* __restrict__ x, const int* __restrict__ row2pair,
                         __bf16* __restrict__ XR) {
  int row = blockIdx.x;
  int pair = row2pair[row];
  int c = threadIdx.x * 4;
  __bf16* dst = XR + (size_t)row * D_MODEL + c;
  if (pair < 0) {
    bf16x4 z = {(__bf16)0.f, (__bf16)0.f, (__bf16)0.f, (__bf16)0.f};
    *(bf16x4*)dst = z;
  } else {
    int t = pair >> 1;
    float4 v = *(const float4*)(x + (size_t)t * D_MODEL + c);
    bf16x4 o = {(__bf16)v.x, (__bf16)v.y, (__bf16)v.z, (__bf16)v.w};
    *(bf16x4*)dst = o;
  }
}

// ---------------- transpose-convert weights: fp32 [E][R][C] -> bf16 [E][C][R] ----
__global__ void k_convT(const float* __restrict__ in, __bf16* __restrict__ out,
                        int R, int C) {
  __shared__ __bf16 tile[64][68];
  int e = blockIdx.z;
  const float* ip = in + (size_t)e * R * C + (size_t)(blockIdx.y * 64) * C + blockIdx.x * 64;
  __bf16* op = out + (size_t)e * R * C + (size_t)(blockIdx.x * 64) * R + blockIdx.y * 64;
#pragma unroll
  for (int it = 0; it < 4; it++) {
    int idx = it * 1024 + threadIdx.x * 4;
    int lr = idx >> 6, lc = idx & 63;
    float4 v = *(const float4*)(ip + (size_t)lr * C + lc);
    bf16x4 o = {(__bf16)v.x, (__bf16)v.y, (__bf16)v.z, (__bf16)v.w};
    *(bf16x4*)&tile[lr][lc] = o;
  }
  __syncthreads();
#pragma unroll
  for (int it = 0; it < 4; it++) {
    int idx = it * 1024 + threadIdx.x * 4;
    int lc = idx >> 6, lr = idx & 63;
    bf16x4 o = {tile[lr + 0][lc], tile[lr + 1][lc], tile[lr + 2][lc], tile[lr + 3][lc]};
    *(bf16x4*)(op + (size_t)lc * R + lr) = o;
  }
}

// =====================================================================
// Pipelined GEMMs: 256-row M-tile, BK=64, 8 waves (512 thr), double-buffered
// LDS with XOR-swizzled layout (linear global_load_lds dest + pre-swizzled
// global source + swizzled ds_read addr), counted vmcnt (never drains to 0
// in steady state), raw s_barrier, setprio around MFMA clusters.
//
// LDS layout per slot: [row][seg'] with seg' = seg ^ (row&7), 16B segs,
// 128 B/row. One global_load_lds instr stages 8 rows (1 KB): lane l writes
// LDS (row=c*8 + l>>3, seg'=l&7) so its global source seg = (l&7)^(l>>3).
// Frag reads (32x32x16): lane reads row (base + l&31), seg = kc*2 + (l>>5);
// addr = row*128 + (axr ^ (kc<<5)), axr = ((l>>5)^(l&7))<<4  -> bank-uniform.
// =====================================================================

// ---------------- GEMM1: H = gelu(XR @ W1[e] + b1[e]) -> bf16 ----------------
// BM=256, BN=256, 8 waves as 2Mx4N (wave tile 128x64), 4 phases / K-tile.
__global__ __launch_bounds__(512, 2) void k_gemm1(
    const __bf16* __restrict__ XR, const __bf16* __restrict__ W1T,
    const float* __restrict__ b1, __bf16* __restrict__ H,
    const int* __restrict__ t2e, const int* __restrict__ trow,
    const int* __restrict__ tlim) {
  __shared__ __align__(16) char lds[2][65536];  // [slot][A 32K | B 32K]
  const int mt = blockIdx.y;
  const int e = t2e[mt];
  if (e < 0) return;
  const int rowBase = trow[mt];
  const int lim = tlim[mt];
  const int n0 = blockIdx.x * 256;

  const int tid = threadIdx.x;
  const int l = tid & 63;
  const int w = tid >> 6;
  const int wm = (w >> 2) * 128;
  const int wn = (w & 3) * 64;
  const int l31 = l & 31;
  const int rsub = l >> 3;                 // row within 8-row chunk
  const int sg = (l & 7) ^ rsub;           // pre-swizzled global 16B-seg

  // per-thread staging sources: A chunks w+8i (i=0..3), B chunks w+8i
  const char* srcA[4]; const char* srcB[4];
#pragma unroll
  for (int i = 0; i < 4; i++) {
    int ra = rowBase + 8 * (w + 8 * i) + rsub;
    if (ra > CAP_ROWS - 1) ra = CAP_ROWS - 1;   // tail-tile clamp (rows discarded)
    srcA[i] = (const char*)(XR + (size_t)ra * D_MODEL) + sg * 16;
    int rb = n0 + 8 * (w + 8 * i) + rsub;
    srcB[i] = (const char*)(W1T + (size_t)e * ((size_t)D_FF * D_MODEL)
                                + (size_t)rb * D_MODEL) + sg * 16;
  }
  const int axr = ((l >> 5) ^ (l & 7)) << 4;

  f32x16 acc[4][2];
#pragma unroll
  for (int i = 0; i < 4; i++)
#pragma unroll
    for (int j = 0; j < 2; j++) acc[i][j] = (f32x16)(0.f);

  // prologue: stage K-tile 0 into slot 0, drain, barrier
  {
    char* sAw = &lds[0][0];
    char* sBw = sAw + 32768;
#pragma unroll
    for (int i = 0; i < 4; i++) {
      async_copy16(srcA[i], sAw + (w + 8 * i) * 1024);
      async_copy16(srcB[i], sBw + (w + 8 * i) * 1024);
    }
    asm volatile("s_waitcnt vmcnt(0)" ::: "memory");
    wg_barrier();
  }

  bf16x8 A[2][4], B[2][4];   // A: current m-half [f][kc]; B: both n-frags [tj][kc]
#pragma unroll 2
  for (int t = 0; t < 16; t++) {
    const int slot = t & 1;
    const char* sAr = &lds[0][0] + slot * 65536;
    const char* sBr = sAr + 32768;
    char* sAw = &lds[0][0] + (slot ^ 1) * 65536;
    char* sBw = sAw + 32768;
    const bool hn = (t + 1) < 16;
    const size_t ko = (size_t)(t + 1) * BKB;

    // -- phase 0: stage pair 0 for t+1, counted boundary wait, read A(mh0)+B(tj0)
    if (hn) {
      async_copy16(srcA[0] + ko, sAw + w * 1024);
      async_copy16(srcB[0] + ko, sBw + w * 1024);
      asm volatile("s_waitcnt vmcnt(2)" ::: "memory");  // tile t's 8 landed; 2 newest fly
    } else {
      asm volatile("s_waitcnt vmcnt(0)" ::: "memory");
    }
    wg_barrier();
#pragma unroll
    for (int f = 0; f < 2; f++)
#pragma unroll
      for (int kc = 0; kc < 4; kc++)
        A[f][kc] = *(const bf16x8*)(sAr + (wm + f * 32 + l31) * BKB + (axr ^ (kc << 5)));
#pragma unroll
    for (int kc = 0; kc < 4; kc++)
      B[0][kc] = *(const bf16x8*)(sBr + (wn + l31) * BKB + (axr ^ (kc << 5)));
    __builtin_amdgcn_s_setprio(1);
#pragma unroll
    for (int kc = 0; kc < 4; kc++)
#pragma unroll
      for (int f = 0; f < 2; f++)
        acc[f][0] = __builtin_amdgcn_mfma_f32_32x32x16_bf16(A[f][kc], B[0][kc], acc[f][0], 0, 0, 0);
    __builtin_amdgcn_s_setprio(0);
    wg_barrier();

    // -- phase 1: read B(tj1); stage pair 1
#pragma unroll
    for (int kc = 0; kc < 4; kc++)
      B[1][kc] = *(const bf16x8*)(sBr + (wn + 32 + l31) * BKB + (axr ^ (kc << 5)));
    if (hn) {
      async_copy16(srcA[1] + ko, sAw + (8 + w) * 1024);
      async_copy16(srcB[1] + ko, sBw + (8 + w) * 1024);
    }
    wg_barrier();
    __builtin_amdgcn_s_setprio(1);
#pragma unroll
    for (int kc = 0; kc < 4; kc++)
#pragma unroll
      for (int f = 0; f < 2; f++)
        acc[f][1] = __builtin_amdgcn_mfma_f32_32x32x16_bf16(A[f][kc], B[1][kc], acc[f][1], 0, 0, 0);
    __builtin_amdgcn_s_setprio(0);
    wg_barrier();

    // -- phase 2: read A(mh1); stage pair 2
#pragma unroll
    for (int f = 0; f < 2; f++)
#pragma unroll
      for (int kc = 0; kc < 4; kc++)
        A[f][kc] = *(const bf16x8*)(sAr + (wm + 64 + f * 32 + l31) * BKB + (axr ^ (kc << 5)));
    if (hn) {
      async_copy16(srcA[2] + ko, sAw + (16 + w) * 1024);
      async_copy16(srcB[2] + ko, sBw + (16 + w) * 1024);
    }
    wg_barrier();
    __builtin_amdgcn_s_setprio(1);
#pragma unroll
    for (int kc = 0; kc < 4; kc++)
#pragma unroll
      for (int f = 0; f < 2; f++)
        acc[2 + f][0] = __builtin_amdgcn_mfma_f32_32x32x16_bf16(A[f][kc], B[0][kc], acc[2 + f][0], 0, 0, 0);
    __builtin_amdgcn_s_setprio(0);
    wg_barrier();

    // -- phase 3: stage pair 3
    if (hn) {
      async_copy16(srcA[3] + ko, sAw + (24 + w) * 1024);
      async_copy16(srcB[3] + ko, sBw + (24 + w) * 1024);
    }
    wg_barrier();
    __builtin_amdgcn_s_setprio(1);
#pragma unroll
    for (int kc = 0; kc < 4; kc++)
#pragma unroll
      for (int f = 0; f < 2; f++)
        acc[2 + f][1] = __builtin_amdgcn_mfma_f32_32x32x16_bf16(A[f][kc], B[1][kc], acc[2 + f][1], 0, 0, 0);
    __builtin_amdgcn_s_setprio(0);
    wg_barrier();
  }

  // epilogue: C/D layout col=lane&31, row=(r&3)+8*(r>>2)+4*(lane>>5)
  const int half = l >> 5;
  int colv[2]; float biasv[2];
#pragma unroll
  for (int tj = 0; tj < 2; tj++) {
    colv[tj] = n0 + wn + tj * 32 + l31;
    biasv[tj] = b1[e * D_FF + colv[tj]];
  }
#pragma unroll
  for (int ti = 0; ti < 4; ti++)
#pragma unroll
    for (int r = 0; r < 16; r++) {
      int lr = wm + ti * 32 + (r & 3) + 8 * (r >> 2) + 4 * half;
      if (lr < lim) {
        size_t row = (size_t)(rowBase + lr);
#pragma unroll
        for (int tj = 0; tj < 2; tj++)
          H[row * D_FF + colv[tj]] = (__bf16)gelu_fast(acc[ti][tj][r] + biasv[tj]);
      }
    }
}

// ---------------- GEMM2: out[t] += w * (H @ W2[e] + b2[e])  (fused combine) ----
// BM=256, BN=128, 8 waves as 4Mx2N (wave tile 64x64), 2 phases / K-tile.
__global__ __launch_bounds__(512, 2) void k_gemm2(
    const __bf16* __restrict__ H, const __bf16* __restrict__ W2T,
    const float* __restrict__ b2, float* __restrict__ out,
    const int* __restrict__ row2pair, const float* __restrict__ pairW,
    const int* __restrict__ t2e, const int* __restrict__ trow,
    const int* __restrict__ tlim) {
  __shared__ __align__(16) char lds[2][49152];  // [slot][A 32K | B 16K]
  const int mt = blockIdx.y;
  const int e = t2e[mt];
  if (e < 0) return;
  const int rowBase = trow[mt];
  const int lim = tlim[mt];
  const int n0 = blockIdx.x * 128;

  const int tid = threadIdx.x;
  const int l = tid & 63;
  const int w = tid >> 6;
  const int wm = (w >> 1) * 64;
  const int wn = (w & 1) * 64;
  const int l31 = l & 31;
  const int rsub = l >> 3;
  const int sg = (l & 7) ^ rsub;

  const char* srcA[4]; const char* srcB[2];
#pragma unroll
  for (int i = 0; i < 4; i++) {
    int ra = rowBase + 8 * (w + 8 * i) + rsub;
    if (ra > CAP_ROWS - 1) ra = CAP_ROWS - 1;
    srcA[i] = (const char*)(H + (size_t)ra * D_FF) + sg * 16;
  }
#pragma unroll
  for (int i = 0; i < 2; i++) {
    int rb = n0 + 8 * (w + 8 * i) + rsub;
    srcB[i] = (const char*)(W2T + (size_t)e * ((size_t)D_MODEL * D_FF)
                                + (size_t)rb * D_FF) + sg * 16;
  }
  const int axr = ((l >> 5) ^ (l & 7)) << 4;

  f32x16 acc[2][2];
#pragma unroll
  for (int i = 0; i < 2; i++)
#pragma unroll
    for (int j = 0; j < 2; j++) acc[i][j] = (f32x16)(0.f);

  // prologue: stage K-tile 0 into slot 0 (6 issues), drain, barrier
  {
    char* sAw = &lds[0][0];
    char* sBw = sAw + 32768;
#pragma unroll
    for (int i = 0; i < 4; i++) async_copy16(srcA[i], sAw + (w + 8 * i) * 1024);
#pragma unroll
    for (int i = 0; i < 2; i++) async_copy16(srcB[i], sBw + (w + 8 * i) * 1024);
    asm volatile("s_waitcnt vmcnt(0)" ::: "memory");
    wg_barrier();
  }

  bf16x8 A[4], B[2][4];
#pragma unroll 2
  for (int t = 0; t < 64; t++) {
    const int slot = t & 1;
    const char* sAr = &lds[0][0] + slot * 49152;
    const char* sBr = sAr + 32768;
    char* sAw = &lds[0][0] + (slot ^ 1) * 49152;
    char* sBw = sAw + 32768;
    const bool hn = (t + 1) < 64;
    const size_t ko = (size_t)(t + 1) * BKB;

    // -- phase 0: stage A0,B0,A1,B1 for t+1, counted wait, read A(ti0)+B(both)
    if (hn) {
      async_copy16(srcA[0] + ko, sAw + w * 1024);
      async_copy16(srcB[0] + ko, sBw + w * 1024);
      async_copy16(srcA[1] + ko, sAw + (8 + w) * 1024);
      async_copy16(srcB[1] + ko, sBw + (8 + w) * 1024);
      asm volatile("s_waitcnt vmcnt(4)" ::: "memory");  // tile t's 6 landed; 4 newest fly
    } else {
      asm volatile("s_waitcnt vmcnt(0)" ::: "memory");
    }
    wg_barrier();
#pragma unroll
    for (int kc = 0; kc < 4; kc++)
      A[kc] = *(const bf16x8*)(sAr + (wm + l31) * BKB + (axr ^ (kc << 5)));
#pragma unroll
    for (int tj = 0; tj < 2; tj++)
#pragma unroll
      for (int kc = 0; kc < 4; kc++)
        B[tj][kc] = *(const bf16x8*)(sBr + (wn + tj * 32 + l31) * BKB + (axr ^ (kc << 5)));
    __builtin_amdgcn_s_setprio(1);
#pragma unroll
    for (int kc = 0; kc < 4; kc++)
#pragma unroll
      for (int tj = 0; tj < 2; tj++)
        acc[0][tj] = __builtin_amdgcn_mfma_f32_32x32x16_bf16(A[kc], B[tj][kc], acc[0][tj], 0, 0, 0);
    __builtin_amdgcn_s_setprio(0);
    wg_barrier();

    // -- phase 1: read A(ti1); stage A2,A3
#pragma unroll
    for (int kc = 0; kc < 4; kc++)
      A[kc] = *(const bf16x8*)(sAr + (wm + 32 + l31) * BKB + (axr ^ (kc << 5)));
    if (hn) {
      async_copy16(srcA[2] + ko, sAw + (16 + w) * 1024);
      async_copy16(srcA[3] + ko, sAw + (24 + w) * 1024);
    }
    wg_barrier();
    __builtin_amdgcn_s_setprio(1);
#pragma unroll
    for (int kc = 0; kc < 4; kc++)
#pragma unroll
      for (int tj = 0; tj < 2; tj++)
        acc[1][tj] = __builtin_amdgcn_mfma_f32_32x32x16_bf16(A[kc], B[tj][kc], acc[1][tj], 0, 0, 0);
    __builtin_amdgcn_s_setprio(0);
    wg_barrier();
  }

  // epilogue: fused combine — exactly 2 commutative fp32 atomic adds per element
  const int half = l >> 5;
  int colv[2]; float biasv[2];
#pragma unroll
  for (int tj = 0; tj < 2; tj++) {
    colv[tj] = n0 + wn + tj * 32 + l31;
    biasv[tj] = b2[e * D_MODEL + colv[tj]];
  }
#pragma unroll
  for (int ti = 0; ti < 2; ti++)
#pragma unroll
    for (int r = 0; r < 16; r++) {
      int lr = wm + ti * 32 + (r & 3) + 8 * (r >> 2) + 4 * half;
      if (lr >= lim) continue;
      int pair = row2pair[rowBase + lr];
      if (pair < 0) continue;
      float pw = pairW[pair];
      size_t tok = (size_t)(pair >> 1);
#pragma unroll
      for (int tj = 0; tj < 2; tj++)
        atomicAdd(out + tok * D_MODEL + colv[tj], pw * (acc[ti][tj][r] + biasv[tj]));
    }
}

extern "C" void kernel_launch(void* const* d_in, const int* in_sizes, int n_in,
                              void* d_out, int out_size, void* d_ws, size_t ws_size,
                              hipStream_t stream) {
  const float* x  = (const float*)d_in[0];
  const float* Wg = (const float*)d_in[1];
  const float* bg = (const float*)d_in[2];
  const float* W1 = (const float*)d_in[3];
  const float* b1 = (const float*)d_in[4];
  const float* W2 = (const float*)d_in[5];
  const float* b2 = (const float*)d_in[6];
  float* out        = (float*)d_out;
  float* logits_out = out + (size_t)T_TOK * D_MODEL;

  char* ws = (char*)d_ws;
  __bf16* W1T = (__bf16*)(ws + OFF_W1T);
  __bf16* W2T = (__bf16*)(ws + OFF_W2T);
  __bf16* H   = (__bf16*)(ws + OFF_H);
  __bf16* XR  = (__bf16*)(ws + OFF_XR);
  char* meta = ws + OFF_META;
  int*   pairExpert = (int*)(meta + M_PAIREXP);
  float* pairW      = (float*)(meta + M_PAIRW);
  int*   row2pair   = (int*)(meta + M_ROW2P);
  int*   counts     = (int*)(meta + M_COUNTS);
  int*   padStart   = (int*)(meta + M_PADST);
  int*   cursor     = (int*)(meta + M_CURSOR);
  int*   t2e        = (int*)(meta + M_T2E);
  int*   trow       = (int*)(meta + M_TROW);
  int*   tlim       = (int*)(meta + M_TLIM);

  // zero the combined output (gemm2 accumulates into it atomically)
  hipMemsetAsync(out, 0, (size_t)T_TOK * D_MODEL * sizeof(float), stream);

  // weight convert+transpose: W1 [E][1024][4096] -> W1T [E][4096][1024]
  k_convT<<<dim3(D_FF / 64, D_MODEL / 64, N_EXP), 256, 0, stream>>>(W1, W1T, D_MODEL, D_FF);
  // W2 [E][4096][1024] -> W2T [E][1024][4096]
  k_convT<<<dim3(D_MODEL / 64, D_FF / 64, N_EXP), 256, 0, stream>>>(W2, W2T, D_FF, D_MODEL);

  k_init<<<(CAP_ROWS + 255) / 256, 256, 0, stream>>>(row2pair);
  k_gate<<<T_TOK / 4, 256, 0, stream>>>(x, Wg, bg, logits_out, pairExpert, pairW);
  k_offsets<<<1, 256, 0, stream>>>(pairExpert, counts, padStart, cursor, t2e, trow, tlim);
  k_place<<<NPAIR / 256, 256, 0, stream>>>(pairExpert, padStart, cursor, row2pair);
  k_gather<<<CAP_ROWS, 256, 0, stream>>>(x, row2pair, XR);

  k_gemm1<<<dim3(D_FF / 256, MAX_T256), 512, 0, stream>>>(XR, W1T, b1, H, t2e, trow, tlim);
  k_gemm2<<<dim3(D_MODEL / 128, MAX_T256), 512, 0, stream>>>(H, W2T, b2, out, row2pair, pairW,
                                                             t2e, trow, tlim);
}

// Round 2
// 932.523 us; speedup vs baseline: 1.0214x; 1.0214x over previous
//
#include <hip/hip_runtime.h>
#include <hip/hip_bf16.h>
#include <math.h>

// ---------------- problem constants ----------------
#define D_MODEL 1024
#define N_EXP   8
#define D_FF    4096
#define T_TOK   8192
#define NPAIR   (T_TOK * 2)              // 16384 token-expert pairs (top-2)
#define CAP_ROWS (NPAIR + N_EXP * 128)   // 17408: worst-case padded rows (128-granular)
#define MAX_T256 72                      // worst-case 256-row M-tiles
#define BKB 128                          // bytes per k-row of a K-tile (64 bf16)
#define SLOT 49152                       // LDS bytes per ring slot: A 32K + B 16K

typedef __attribute__((ext_vector_type(4)))  float  f32x4;
typedef __attribute__((ext_vector_type(16))) float  f32x16;
typedef __attribute__((ext_vector_type(8)))  __bf16 bf16x8;
typedef __attribute__((ext_vector_type(4)))  __bf16 bf16x4;

// ---------------- workspace layout (bytes) ----------------
#define OFF_W1T   0
#define OFF_W2T   67108864
#define OFF_H     134217728
#define OFF_XR    276824064
#define OFF_META  312475648
#define M_PAIREXP 0         // int[16384]
#define M_PAIRW   65536     // float[16384]
#define M_ROW2P   131072    // int[17408]
#define M_COUNTS  200704    // int[8]
#define M_PADST   200736    // int[8]
#define M_CURSOR  200768    // int[8*32]
#define M_T2E     201792    // int[72]
#define M_TROW    202336    // int[72]
#define M_TLIM    202880    // int[72]

__device__ __forceinline__ void async_copy16(const void* g, void* s) {
  __builtin_amdgcn_global_load_lds(
      (const __attribute__((address_space(1))) void*)g,
      (__attribute__((address_space(3))) void*)s, 16, 0, 0);
}

__device__ __forceinline__ void wg_barrier() {
  asm volatile("" ::: "memory");
  __builtin_amdgcn_s_barrier();
  asm volatile("" ::: "memory");
}

__device__ __forceinline__ float gelu_fast(float v) {
  float u = 1.5957691216057308f * (v + 0.044715f * v * v * v);
  return v * __builtin_amdgcn_rcpf(1.f + __expf(-u));
}

// ---------------- gating ----------------
__global__ void k_gate(const float* __restrict__ x, const float* __restrict__ Wg,
                       const float* __restrict__ bg, float* __restrict__ logits_out,
                       int* __restrict__ pairExpert, float* __restrict__ pairW) {
  const int t    = blockIdx.x * 4 + (threadIdx.x >> 6);
  const int lane = threadIdx.x & 63;
  const float* xp = x + (size_t)t * D_MODEL;
  float acc[8];
#pragma unroll
  for (int e = 0; e < 8; e++) acc[e] = 0.f;
#pragma unroll
  for (int i = 0; i < 16; i++) {
    int d = i * 64 + lane;
    float xv = xp[d];
    const float4* wr = (const float4*)(Wg + d * 8);
    float4 w0 = wr[0], w1 = wr[1];
    acc[0] += xv * w0.x; acc[1] += xv * w0.y; acc[2] += xv * w0.z; acc[3] += xv * w0.w;
    acc[4] += xv * w1.x; acc[5] += xv * w1.y; acc[6] += xv * w1.z; acc[7] += xv * w1.w;
  }
#pragma unroll
  for (int e = 0; e < 8; e++)
#pragma unroll
    for (int off = 32; off > 0; off >>= 1) acc[e] += __shfl_down(acc[e], off);
  if (lane == 0) {
    float l[8];
#pragma unroll
    for (int e = 0; e < 8; e++) { l[e] = acc[e] + bg[e]; logits_out[t * 8 + e] = l[e]; }
    float m = l[0];
#pragma unroll
    for (int e = 1; e < 8; e++) m = fmaxf(m, l[e]);
    float p[8], s = 0.f;
#pragma unroll
    for (int e = 0; e < 8; e++) { p[e] = expf(l[e] - m); s += p[e]; }
    float inv = 1.0f / s;
    int i1 = 0;
#pragma unroll
    for (int e = 1; e < 8; e++) if (l[e] > l[i1]) i1 = e;
    int i2 = (i1 == 0) ? 1 : 0;
#pragma unroll
    for (int e = 0; e < 8; e++) if (e != i1 && l[e] > l[i2]) i2 = e;
    pairExpert[t * 2 + 0] = i1; pairW[t * 2 + 0] = p[i1] * inv;
    pairExpert[t * 2 + 1] = i2; pairW[t * 2 + 1] = p[i2] * inv;
  }
}

// ---------------- routing metadata ----------------
__global__ void k_init(int* __restrict__ row2pair) {
  int i = blockIdx.x * 256 + threadIdx.x;
  if (i < CAP_ROWS) row2pair[i] = -1;
}

__global__ void k_offsets(const int* __restrict__ pairExpert, int* __restrict__ counts,
                          int* __restrict__ padStart, int* __restrict__ cursor,
                          int* __restrict__ t2e, int* __restrict__ trow,
                          int* __restrict__ tlim) {
  __shared__ int hist[8];
  int tid = threadIdx.x;
  if (tid < 8) hist[tid] = 0;
  __syncthreads();
  for (int i = tid; i < NPAIR; i += 256) atomicAdd(&hist[pairExpert[i]], 1);
  __syncthreads();
  if (tid == 0) {
    int run = 0, nt = 0;
    for (int e = 0; e < 8; e++) {
      counts[e] = hist[e]; padStart[e] = run; cursor[e * 32] = 0;
      int rows = ((hist[e] + 127) >> 7) << 7;
      for (int r0 = 0; r0 < rows; r0 += 256) {
        t2e[nt] = e; trow[nt] = run + r0;
        int rem = rows - r0;
        tlim[nt] = rem < 256 ? rem : 256;
        nt++;
      }
      run += rows;
    }
    for (; nt < MAX_T256; nt++) t2e[nt] = -1;
  }
}

__global__ void k_place(const int* __restrict__ pairExpert, const int* __restrict__ padStart,
                        int* __restrict__ cursor, int* __restrict__ row2pair) {
  int p = blockIdx.x * 256 + threadIdx.x;
  if (p >= NPAIR) return;
  int e = pairExpert[p];
  int r = atomicAdd(&cursor[e * 32], 1);
  row2pair[padStart[e] + r] = p;
}

// ---------------- gather x rows -> routed bf16 ----------------
__global__ void k_gather(const float* __restrict__ x, const int* __restrict__ row2pair,
                         __bf16* __restrict__ XR) {
  int row = blockIdx.x;
  int pair = row2pair[row];
  int c = threadIdx.x * 4;
  __bf16* dst = XR + (size_t)row * D_MODEL + c;
  if (pair < 0) {
    bf16x4 z = {(__bf16)0.f, (__bf16)0.f, (__bf16)0.f, (__bf16)0.f};
    *(bf16x4*)dst = z;
  } else {
    int t = pair >> 1;
    float4 v = *(const float4*)(x + (size_t)t * D_MODEL + c);
    bf16x4 o = {(__bf16)v.x, (__bf16)v.y, (__bf16)v.z, (__bf16)v.w};
    *(bf16x4*)dst = o;
  }
}

// ---------------- transpose-convert weights ----------------
__global__ void k_convT(const float* __restrict__ in, __bf16* __restrict__ out,
                        int R, int C) {
  __shared__ __bf16 tile[64][68];
  int e = blockIdx.z;
  const float* ip = in + (size_t)e * R * C + (size_t)(blockIdx.y * 64) * C + blockIdx.x * 64;
  __bf16* op = out + (size_t)e * R * C + (size_t)(blockIdx.x * 64) * R + blockIdx.y * 64;
#pragma unroll
  for (int it = 0; it < 4; it++) {
    int idx = it * 1024 + threadIdx.x * 4;
    int lr = idx >> 6, lc = idx & 63;
    float4 v = *(const float4*)(ip + (size_t)lr * C + lc);
    bf16x4 o = {(__bf16)v.x, (__bf16)v.y, (__bf16)v.z, (__bf16)v.w};
    *(bf16x4*)&tile[lr][lc] = o;
  }
  __syncthreads();
#pragma unroll
  for (int it = 0; it < 4; it++) {
    int idx = it * 1024 + threadIdx.x * 4;
    int lc = idx >> 6, lr = idx & 63;
    bf16x4 o = {tile[lr + 0][lc], tile[lr + 1][lc], tile[lr + 2][lc], tile[lr + 3][lc]};
    *(bf16x4*)(op + (size_t)lc * R + lr) = o;
  }
}

// =====================================================================
// Ring-3 pipelined GEMM structure, both GEMMs:
//   BM=256, BN=128, BK=64, 512 thr = 8 waves as 4Mx2N (wave tile 64x64).
//   LDS: 3 slots x 48KB (A 32K | B 16K). Tile t reads slot t%3; stages
//   tile t+2 into slot (t+2)%3 (that slot was last read at t-1, so the
//   single end-of-tile barrier makes the overwrite WAR-safe).
//   Per K-tile: ds_reads issued FIRST (latency hides under MFMA), then
//   6 global_load_lds for t+2, then 16 MFMA, then s_waitcnt vmcnt(6)
//   (t+1's 6 loads landed; t+2's 6 still in flight), then ONE s_barrier.
//   vmcnt never drains to 0 in steady state; prefetch depth = 2 K-tiles.
// LDS swizzle (verified r1): chunk c = 8 rows; lane l writes row c*8+(l>>3),
// 16B-seg (l&7); global src seg = (l&7)^(l>>3); read addr row*128 +
// (axr ^ (kc<<5)), axr = ((l>>5)^(l&7))<<4.
// =====================================================================

#define STAGE(SW, T)                                                       \
  do {                                                                     \
    size_t _ko = (size_t)(T) * BKB;                                        \
    _Pragma("unroll")                                                      \
    for (int _i = 0; _i < 4; _i++)                                         \
      async_copy16(srcA[_i] + _ko, (SW) + (w + 8 * _i) * 1024);            \
    _Pragma("unroll")                                                      \
    for (int _i = 0; _i < 2; _i++)                                         \
      async_copy16(srcB[_i] + _ko, (SW) + 32768 + (w + 8 * _i) * 1024);    \
  } while (0)

#define LOADFRAG(SR)                                                       \
  _Pragma("unroll")                                                        \
  for (int _mi = 0; _mi < 2; _mi++)                                        \
    _Pragma("unroll")                                                      \
    for (int _kc = 0; _kc < 4; _kc++)                                      \
      Af[_mi][_kc] = *(const bf16x8*)((SR) + (wm + _mi * 32 + l31) * BKB + (axr ^ (_kc << 5))); \
  _Pragma("unroll")                                                        \
  for (int _nj = 0; _nj < 2; _nj++)                                        \
    _Pragma("unroll")                                                      \
    for (int _kc = 0; _kc < 4; _kc++)                                      \
      Bf[_nj][_kc] = *(const bf16x8*)((SR) + 32768 + (wn + _nj * 32 + l31) * BKB + (axr ^ (_kc << 5)));

#define MFMAS                                                              \
  __builtin_amdgcn_s_setprio(1);                                           \
  _Pragma("unroll")                                                        \
  for (int _kc = 0; _kc < 4; _kc++)                                        \
    _Pragma("unroll")                                                      \
    for (int _mi = 0; _mi < 2; _mi++)                                      \
      _Pragma("unroll")                                                    \
      for (int _nj = 0; _nj < 2; _nj++)                                    \
        acc[_mi][_nj] = __builtin_amdgcn_mfma_f32_32x32x16_bf16(           \
            Af[_mi][_kc], Bf[_nj][_kc], acc[_mi][_nj], 0, 0, 0);           \
  __builtin_amdgcn_s_setprio(0);

#define BODY_MAIN(T, SR, SW)                                               \
  do { bf16x8 Af[2][4], Bf[2][4]; LOADFRAG(SR); STAGE(SW, (T) + 2); MFMAS; \
       asm volatile("s_waitcnt vmcnt(6)" ::: "memory"); wg_barrier(); } while (0)
#define BODY_NOST(SR)                                                      \
  do { bf16x8 Af[2][4], Bf[2][4]; LOADFRAG(SR); MFMAS;                     \
       asm volatile("s_waitcnt vmcnt(0)" ::: "memory"); wg_barrier(); } while (0)
#define BODY_LAST(SR)                                                      \
  do { bf16x8 Af[2][4], Bf[2][4]; LOADFRAG(SR); MFMAS; } while (0)

// ---------------- GEMM1: H = gelu(XR @ W1[e] + b1[e]) -> bf16 ----------------
__global__ __launch_bounds__(512, 2) void k_gemm1(
    const __bf16* __restrict__ XR, const __bf16* __restrict__ W1T,
    const float* __restrict__ b1, __bf16* __restrict__ H,
    const int* __restrict__ t2e, const int* __restrict__ trow,
    const int* __restrict__ tlim) {
  __shared__ __align__(16) char lds[3][SLOT];
  const int mt = blockIdx.y;
  const int e = t2e[mt];
  if (e < 0) return;
  const int rowBase = trow[mt];
  const int lim = tlim[mt];
  const int n0 = blockIdx.x * 128;

  const int tid = threadIdx.x;
  const int l = tid & 63;
  const int w = tid >> 6;
  const int wm = (w >> 1) * 64;
  const int wn = (w & 1) * 64;
  const int l31 = l & 31;
  const int half = l >> 5;
  const int rsub = l >> 3;
  const int sg = (l & 7) ^ rsub;

  const char* srcA[4]; const char* srcB[2];
#pragma unroll
  for (int i = 0; i < 4; i++) {
    int ra = rowBase + 8 * (w + 8 * i) + rsub;
    if (ra > CAP_ROWS - 1) ra = CAP_ROWS - 1;
    srcA[i] = (const char*)(XR + (size_t)ra * D_MODEL) + sg * 16;
  }
#pragma unroll
  for (int i = 0; i < 2; i++) {
    int rb = n0 + 8 * (w + 8 * i) + rsub;
    srcB[i] = (const char*)(W1T + (size_t)e * ((size_t)D_FF * D_MODEL)
                                + (size_t)rb * D_MODEL) + sg * 16;
  }
  const int axr = ((l >> 5) ^ (l & 7)) << 4;

  f32x16 acc[2][2];
#pragma unroll
  for (int i = 0; i < 2; i++)
#pragma unroll
    for (int j = 0; j < 2; j++) acc[i][j] = (f32x16)(0.f);

  char* s0 = &lds[0][0]; char* s1 = &lds[1][0]; char* s2 = &lds[2][0];

  // prologue: stage tiles 0,1; wait tile 0; barrier
  STAGE(s0, 0);
  STAGE(s1, 1);
  asm volatile("s_waitcnt vmcnt(6)" ::: "memory");
  wg_barrier();

  // K = 1024 -> 16 K-tiles
#pragma unroll 1
  for (int tg = 0; tg < 4; tg++) {
    BODY_MAIN(3 * tg + 0, s0, s2);
    BODY_MAIN(3 * tg + 1, s1, s0);
    BODY_MAIN(3 * tg + 2, s2, s1);
  }
  BODY_MAIN(12, s0, s2);
  BODY_MAIN(13, s1, s0);
  BODY_NOST(s2);
  BODY_LAST(s0);

  // epilogue: C/D layout col=lane&31, row=(r&3)+8*(r>>2)+4*(lane>>5)
  int colv[2]; float biasv[2];
#pragma unroll
  for (int nj = 0; nj < 2; nj++) {
    colv[nj] = n0 + wn + nj * 32 + l31;
    biasv[nj] = b1[e * D_FF + colv[nj]];
  }
#pragma unroll
  for (int mi = 0; mi < 2; mi++)
#pragma unroll
    for (int r = 0; r < 16; r++) {
      int lr = wm + mi * 32 + (r & 3) + 8 * (r >> 2) + 4 * half;
      if (lr < lim) {
        size_t row = (size_t)(rowBase + lr);
#pragma unroll
        for (int nj = 0; nj < 2; nj++)
          H[row * D_FF + colv[nj]] = (__bf16)gelu_fast(acc[mi][nj][r] + biasv[nj]);
      }
    }
}

// ---------------- GEMM2: out[t] += w * (H @ W2[e] + b2[e])  (fused combine) ----
__global__ __launch_bounds__(512, 2) void k_gemm2(
    const __bf16* __restrict__ H, const __bf16* __restrict__ W2T,
    const float* __restrict__ b2, float* __restrict__ out,
    const int* __restrict__ row2pair, const float* __restrict__ pairW,
    const int* __restrict__ t2e, const int* __restrict__ trow,
    const int* __restrict__ tlim) {
  __shared__ __align__(16) char lds[3][SLOT];
  const int mt = blockIdx.y;
  const int e = t2e[mt];
  if (e < 0) return;
  const int rowBase = trow[mt];
  const int lim = tlim[mt];
  const int n0 = blockIdx.x * 128;

  const int tid = threadIdx.x;
  const int l = tid & 63;
  const int w = tid >> 6;
  const int wm = (w >> 1) * 64;
  const int wn = (w & 1) * 64;
  const int l31 = l & 31;
  const int half = l >> 5;
  const int rsub = l >> 3;
  const int sg = (l & 7) ^ rsub;

  const char* srcA[4]; const char* srcB[2];
#pragma unroll
  for (int i = 0; i < 4; i++) {
    int ra = rowBase + 8 * (w + 8 * i) + rsub;
    if (ra > CAP_ROWS - 1) ra = CAP_ROWS - 1;
    srcA[i] = (const char*)(H + (size_t)ra * D_FF) + sg * 16;
  }
#pragma unroll
  for (int i = 0; i < 2; i++) {
    int rb = n0 + 8 * (w + 8 * i) + rsub;
    srcB[i] = (const char*)(W2T + (size_t)e * ((size_t)D_MODEL * D_FF)
                                + (size_t)rb * D_FF) + sg * 16;
  }
  const int axr = ((l >> 5) ^ (l & 7)) << 4;

  f32x16 acc[2][2];
#pragma unroll
  for (int i = 0; i < 2; i++)
#pragma unroll
    for (int j = 0; j < 2; j++) acc[i][j] = (f32x16)(0.f);

  char* s0 = &lds[0][0]; char* s1 = &lds[1][0]; char* s2 = &lds[2][0];

  STAGE(s0, 0);
  STAGE(s1, 1);
  asm volatile("s_waitcnt vmcnt(6)" ::: "memory");
  wg_barrier();

  // K = 4096 -> 64 K-tiles
#pragma unroll 1
  for (int tg = 0; tg < 20; tg++) {
    BODY_MAIN(3 * tg + 0, s0, s2);
    BODY_MAIN(3 * tg + 1, s1, s0);
    BODY_MAIN(3 * tg + 2, s2, s1);
  }
  BODY_MAIN(60, s0, s2);
  BODY_MAIN(61, s1, s0);
  BODY_NOST(s2);
  BODY_LAST(s0);

  // epilogue: fused combine — 2 commutative fp32 atomic adds per element
  int colv[2]; float biasv[2];
#pragma unroll
  for (int nj = 0; nj < 2; nj++) {
    colv[nj] = n0 + wn + nj * 32 + l31;
    biasv[nj] = b2[e * D_MODEL + colv[nj]];
  }
#pragma unroll
  for (int mi = 0; mi < 2; mi++)
#pragma unroll
    for (int r = 0; r < 16; r++) {
      int lr = wm + mi * 32 + (r & 3) + 8 * (r >> 2) + 4 * half;
      if (lr >= lim) continue;
      int pair = row2pair[rowBase + lr];
      if (pair < 0) continue;
      float pw = pairW[pair];
      size_t tok = (size_t)(pair >> 1);
#pragma unroll
      for (int nj = 0; nj < 2; nj++)
        atomicAdd(out + tok * D_MODEL + colv[nj], pw * (acc[mi][nj][r] + biasv[nj]));
    }
}

extern "C" void kernel_launch(void* const* d_in, const int* in_sizes, int n_in,
                              void* d_out, int out_size, void* d_ws, size_t ws_size,
                              hipStream_t stream) {
  const float* x  = (const float*)d_in[0];
  const float* Wg = (const float*)d_in[1];
  const float* bg = (const float*)d_in[2];
  const float* W1 = (const float*)d_in[3];
  const float* b1 = (const float*)d_in[4];
  const float* W2 = (const float*)d_in[5];
  const float* b2 = (const float*)d_in[6];
  float* out        = (float*)d_out;
  float* logits_out = out + (size_t)T_TOK * D_MODEL;

  char* ws = (char*)d_ws;
  __bf16* W1T = (__bf16*)(ws + OFF_W1T);
  __bf16* W2T = (__bf16*)(ws + OFF_W2T);
  __bf16* H   = (__bf16*)(ws + OFF_H);
  __bf16* XR  = (__bf16*)(ws + OFF_XR);
  char* meta = ws + OFF_META;
  int*   pairExpert = (int*)(meta + M_PAIREXP);
  float* pairW      = (float*)(meta + M_PAIRW);
  int*   row2pair   = (int*)(meta + M_ROW2P);
  int*   counts     = (int*)(meta + M_COUNTS);
  int*   padStart   = (int*)(meta + M_PADST);
  int*   cursor     = (int*)(meta + M_CURSOR);
  int*   t2e        = (int*)(meta + M_T2E);
  int*   trow       = (int*)(meta + M_TROW);
  int*   tlim       = (int*)(meta + M_TLIM);

  // zero the combined output (gemm2 accumulates into it atomically)
  hipMemsetAsync(out, 0, (size_t)T_TOK * D_MODEL * sizeof(float), stream);

  k_convT<<<dim3(D_FF / 64, D_MODEL / 64, N_EXP), 256, 0, stream>>>(W1, W1T, D_MODEL, D_FF);
  k_convT<<<dim3(D_MODEL / 64, D_FF / 64, N_EXP), 256, 0, stream>>>(W2, W2T, D_FF, D_MODEL);

  k_init<<<(CAP_ROWS + 255) / 256, 256, 0, stream>>>(row2pair);
  k_gate<<<T_TOK / 4, 256, 0, stream>>>(x, Wg, bg, logits_out, pairExpert, pairW);
  k_offsets<<<1, 256, 0, stream>>>(pairExpert, counts, padStart, cursor, t2e, trow, tlim);
  k_place<<<NPAIR / 256, 256, 0, stream>>>(pairExpert, padStart, cursor, row2pair);
  k_gather<<<CAP_ROWS, 256, 0, stream>>>(x, row2pair, XR);

  k_gemm1<<<dim3(D_FF / 128, MAX_T256), 512, 0, stream>>>(XR, W1T, b1, H, t2e, trow, tlim);
  k_gemm2<<<dim3(D_MODEL / 128, MAX_T256), 512, 0, stream>>>(H, W2T, b2, out, row2pair, pairW,
                                                             t2e, trow, tlim);
}

// Round 3
// 859.748 us; speedup vs baseline: 1.1079x; 1.0846x over previous
//
#include <hip/hip_runtime.h>
#include <hip/hip_bf16.h>
#include <math.h>

// ---------------- problem constants ----------------
#define D_MODEL 1024
#define N_EXP   8
#define D_FF    4096
#define T_TOK   8192
#define NPAIR   (T_TOK * 2)              // 16384 token-expert pairs (top-2)
#define CAP_ROWS (NPAIR + N_EXP * 128)   // 17408: worst-case padded rows
#define MAX_TILES (CAP_ROWS / 128)       // 136 M-tiles (divisible by 8)

typedef __attribute__((ext_vector_type(4)))  float  f32x4;
typedef __attribute__((ext_vector_type(16))) float  f32x16;
typedef __attribute__((ext_vector_type(8)))  __bf16 bf16x8;
typedef __attribute__((ext_vector_type(4)))  __bf16 bf16x4;

// ---------------- workspace layout (bytes) ----------------
#define OFF_W1T   0
#define OFF_W2T   67108864
#define OFF_H     134217728
#define OFF_XR    276824064
#define OFF_META  312475648
#define M_PAIREXP 0         // int[16384]
#define M_PAIRW   65536     // float[16384]
#define M_ROW2P   131072    // int[17408]
#define M_COUNTS  200704    // int[8]
#define M_PADST   200736    // int[8]
#define M_CURSOR  200768    // int[8*32]
#define M_T2E     201792    // int[136]
#define M_TROW    202336    // int[136]

__device__ __forceinline__ void async_copy16(const void* g, void* s) {
  __builtin_amdgcn_global_load_lds(
      (const __attribute__((address_space(1))) void*)g,
      (__attribute__((address_space(3))) void*)s, 16, 0, 0);
}

__device__ __forceinline__ float gelu_fast(float v) {
  float u = 1.5957691216057308f * (v + 0.044715f * v * v * v);
  return v * __builtin_amdgcn_rcpf(1.f + __expf(-u));
}

// ---------------- gating ----------------
__global__ void k_gate(const float* __restrict__ x, const float* __restrict__ Wg,
                       const float* __restrict__ bg, float* __restrict__ logits_out,
                       int* __restrict__ pairExpert, float* __restrict__ pairW) {
  const int t    = blockIdx.x * 4 + (threadIdx.x >> 6);
  const int lane = threadIdx.x & 63;
  const float* xp = x + (size_t)t * D_MODEL;
  float acc[8];
#pragma unroll
  for (int e = 0; e < 8; e++) acc[e] = 0.f;
#pragma unroll
  for (int i = 0; i < 16; i++) {
    int d = i * 64 + lane;
    float xv = xp[d];
    const float4* wr = (const float4*)(Wg + d * 8);
    float4 w0 = wr[0], w1 = wr[1];
    acc[0] += xv * w0.x; acc[1] += xv * w0.y; acc[2] += xv * w0.z; acc[3] += xv * w0.w;
    acc[4] += xv * w1.x; acc[5] += xv * w1.y; acc[6] += xv * w1.z; acc[7] += xv * w1.w;
  }
#pragma unroll
  for (int e = 0; e < 8; e++)
#pragma unroll
    for (int off = 32; off > 0; off >>= 1) acc[e] += __shfl_down(acc[e], off);
  if (lane == 0) {
    float l[8];
#pragma unroll
    for (int e = 0; e < 8; e++) { l[e] = acc[e] + bg[e]; logits_out[t * 8 + e] = l[e]; }
    float m = l[0];
#pragma unroll
    for (int e = 1; e < 8; e++) m = fmaxf(m, l[e]);
    float p[8], s = 0.f;
#pragma unroll
    for (int e = 0; e < 8; e++) { p[e] = expf(l[e] - m); s += p[e]; }
    float inv = 1.0f / s;
    int i1 = 0;
#pragma unroll
    for (int e = 1; e < 8; e++) if (l[e] > l[i1]) i1 = e;
    int i2 = (i1 == 0) ? 1 : 0;
#pragma unroll
    for (int e = 0; e < 8; e++) if (e != i1 && l[e] > l[i2]) i2 = e;
    pairExpert[t * 2 + 0] = i1; pairW[t * 2 + 0] = p[i1] * inv;
    pairExpert[t * 2 + 1] = i2; pairW[t * 2 + 1] = p[i2] * inv;
  }
}

// ---------------- routing metadata ----------------
__global__ void k_init(int* __restrict__ row2pair) {
  int i = blockIdx.x * 256 + threadIdx.x;
  if (i < CAP_ROWS) row2pair[i] = -1;
}

__global__ void k_offsets(const int* __restrict__ pairExpert, int* __restrict__ counts,
                          int* __restrict__ padStart, int* __restrict__ cursor,
                          int* __restrict__ t2e, int* __restrict__ trow) {
  __shared__ int hist[8];
  int tid = threadIdx.x;
  if (tid < 8) hist[tid] = 0;
  __syncthreads();
  for (int i = tid; i < NPAIR; i += 256) atomicAdd(&hist[pairExpert[i]], 1);
  __syncthreads();
  if (tid == 0) {
    int run = 0, nt = 0;
    for (int e = 0; e < 8; e++) {
      counts[e] = hist[e]; padStart[e] = run; cursor[e * 32] = 0;
      int tiles = (hist[e] + 127) >> 7;
      for (int i = 0; i < tiles; i++) { t2e[nt] = e; trow[nt] = run + i * 128; nt++; }
      run += tiles * 128;
    }
    for (; nt < MAX_TILES; nt++) t2e[nt] = -1;
  }
}

__global__ void k_place(const int* __restrict__ pairExpert, const int* __restrict__ padStart,
                        int* __restrict__ cursor, int* __restrict__ row2pair) {
  int p = blockIdx.x * 256 + threadIdx.x;
  if (p >= NPAIR) return;
  int e = pairExpert[p];
  int r = atomicAdd(&cursor[e * 32], 1);
  row2pair[padStart[e] + r] = p;
}

// ---------------- gather x rows -> routed bf16 ----------------
__global__ void k_gather(const float* __restrict__ x, const int* __restrict__ row2pair,
                         __bf16* __restrict__ XR) {
  int row = blockIdx.x;
  int pair = row2pair[row];
  int c = threadIdx.x * 4;
  __bf16* dst = XR + (size_t)row * D_MODEL + c;
  if (pair < 0) {
    bf16x4 z = {(__bf16)0.f, (__bf16)0.f, (__bf16)0.f, (__bf16)0.f};
    *(bf16x4*)dst = z;
  } else {
    int t = pair >> 1;
    float4 v = *(const float4*)(x + (size_t)t * D_MODEL + c);
    bf16x4 o = {(__bf16)v.x, (__bf16)v.y, (__bf16)v.z, (__bf16)v.w};
    *(bf16x4*)dst = o;
  }
}

// ---------------- transpose-convert weights ----------------
__global__ void k_convT(const float* __restrict__ in, __bf16* __restrict__ out,
                        int R, int C) {
  __shared__ __bf16 tile[64][68];
  int e = blockIdx.z;
  const float* ip = in + (size_t)e * R * C + (size_t)(blockIdx.y * 64) * C + blockIdx.x * 64;
  __bf16* op = out + (size_t)e * R * C + (size_t)(blockIdx.x * 64) * R + blockIdx.y * 64;
#pragma unroll
  for (int it = 0; it < 4; it++) {
    int idx = it * 1024 + threadIdx.x * 4;
    int lr = idx >> 6, lc = idx & 63;
    float4 v = *(const float4*)(ip + (size_t)lr * C + lc);
    bf16x4 o = {(__bf16)v.x, (__bf16)v.y, (__bf16)v.z, (__bf16)v.w};
    *(bf16x4*)&tile[lr][lc] = o;
  }
  __syncthreads();
#pragma unroll
  for (int it = 0; it < 4; it++) {
    int idx = it * 1024 + threadIdx.x * 4;
    int lc = idx >> 6, lr = idx & 63;
    bf16x4 o = {tile[lr + 0][lc], tile[lr + 1][lc], tile[lr + 2][lc], tile[lr + 3][lc]};
    *(bf16x4*)(op + (size_t)lc * R + lr) = o;
  }
}

// =====================================================================
// Ring-3 latency-hiding GEMM, small tile for residency:
//   BM=128, BN=128, BK=32, 256 thr = 4 waves as 2Mx2N (wave tile 64x64).
//   LDS: 3 slots x 16KB (A 8K | B 8K) = 48KB -> 3 blocks/CU (launch_bounds 256,3).
//   Body t: STAGE tile t+2 -> slot (t+2)%3 (4 gl_lds/wave), ds_read slot t%3,
//   8 MFMA, sched_barrier(0), s_waitcnt vmcnt(4) (t+1 landed; t+2 in flight),
//   one s_barrier. Per-wave outstanding stays at 8 loads -> ~96KB/CU in flight.
// LDS swizzle (conflict-free, both-sides): row r, 16B-seg s stored at
//   physical seg s ^ ((r>>1)&3). gl_lds dest linear (lane*16); lane l pulls
//   global seg (l&3)^((l>>3)&3) of row 16c+(l>>2). Read: lane l reads row
//   base+(l&31), byte (aoff ^ (kc<<5)), aoff = ((half ^ ((l>>1)&3))<<4.
//   -> 32 lanes cover all 8 bank-quads per cycle group.
// =====================================================================

#define STG(SW, T)                                                         \
  do {                                                                     \
    size_t _ko = (size_t)(T) * 64;                                         \
    async_copy16(srcA0 + _ko, (SW) + w * 1024);                            \
    async_copy16(srcA1 + _ko, (SW) + (w + 4) * 1024);                      \
    async_copy16(srcB0 + _ko, (SW) + 8192 + w * 1024);                     \
    async_copy16(srcB1 + _ko, (SW) + 8192 + (w + 4) * 1024);               \
  } while (0)

#define LDF(SR)                                                            \
  do {                                                                     \
    _Pragma("unroll")                                                      \
    for (int mi = 0; mi < 2; mi++)                                         \
      _Pragma("unroll")                                                    \
      for (int kc = 0; kc < 2; kc++)                                       \
        Af[mi][kc] = *(const bf16x8*)((SR) + (wm + mi * 32 + l31) * 64 + (aoff ^ (kc << 5))); \
    _Pragma("unroll")                                                      \
    for (int nj = 0; nj < 2; nj++)                                         \
      _Pragma("unroll")                                                    \
      for (int kc = 0; kc < 2; kc++)                                       \
        Bf[nj][kc] = *(const bf16x8*)((SR) + 8192 + (wn + nj * 32 + l31) * 64 + (aoff ^ (kc << 5))); \
  } while (0)

#define MFM                                                                \
  do {                                                                     \
    __builtin_amdgcn_s_setprio(1);                                         \
    _Pragma("unroll")                                                      \
    for (int kc = 0; kc < 2; kc++)                                         \
      _Pragma("unroll")                                                    \
      for (int mi = 0; mi < 2; mi++)                                       \
        _Pragma("unroll")                                                  \
        for (int nj = 0; nj < 2; nj++)                                     \
          acc[mi][nj] = __builtin_amdgcn_mfma_f32_32x32x16_bf16(           \
              Af[mi][kc], Bf[nj][kc], acc[mi][nj], 0, 0, 0);               \
    __builtin_amdgcn_s_setprio(0);                                         \
  } while (0)

#define ENDW(N)                                                            \
  do {                                                                     \
    __builtin_amdgcn_sched_barrier(0);                                     \
    asm volatile("s_waitcnt vmcnt(" #N ")" ::: "memory");                  \
    __builtin_amdgcn_s_barrier();                                          \
    asm volatile("" ::: "memory");                                         \
  } while (0)

#define BODY(SR, SW, T) \
  do { bf16x8 Af[2][2], Bf[2][2]; STG(SW, T); LDF(SR); MFM; ENDW(4); } while (0)
#define BODY_N0(SR) \
  do { bf16x8 Af[2][2], Bf[2][2]; LDF(SR); MFM; ENDW(0); } while (0)
#define BODY_LAST(SR) \
  do { bf16x8 Af[2][2], Bf[2][2]; LDF(SR); MFM; } while (0)

// ---------------- GEMM1: H = gelu(XR @ W1[e] + b1[e]) -> bf16 ----------------
// grid 1D = 17*256; XCD swizzle: di = q*256 + nb*8 + r, mt = q*8+r -> the 32
// nb-blocks sharing an A-panel land on one XCD, temporally adjacent.
__global__ __launch_bounds__(256, 3) void k_gemm1(
    const __bf16* __restrict__ XR, const __bf16* __restrict__ W1T,
    const float* __restrict__ b1, __bf16* __restrict__ H,
    const int* __restrict__ t2e, const int* __restrict__ trow) {
  __shared__ __align__(16) char lds[3][16384];
  const int bid = blockIdx.x;
  const int q = bid >> 8, w8 = bid & 255;
  const int nb = w8 >> 3, mt = q * 8 + (w8 & 7);
  const int e = t2e[mt];
  if (e < 0) return;
  const int rowBase = trow[mt];
  const int n0 = nb * 128;

  const int tid = threadIdx.x;
  const int l = tid & 63, w = tid >> 6;
  const int wm = (w >> 1) * 64, wn = (w & 1) * 64;
  const int l31 = l & 31, half = l >> 5;
  const int rsub = l >> 2;
  const int sg = (l & 3) ^ ((l >> 3) & 3);
  const int aoff = ((half ^ ((l >> 1) & 3)) << 4);

  const char* srcA0 = (const char*)(XR + (size_t)(rowBase + 16 * w + rsub) * D_MODEL) + sg * 16;
  const char* srcA1 = srcA0 + (size_t)64 * D_MODEL * 2;
  const __bf16* Bb = W1T + (size_t)e * D_FF * D_MODEL + (size_t)n0 * D_MODEL;
  const char* srcB0 = (const char*)(Bb + (size_t)(16 * w + rsub) * D_MODEL) + sg * 16;
  const char* srcB1 = srcB0 + (size_t)64 * D_MODEL * 2;

  f32x16 acc[2][2];
#pragma unroll
  for (int i = 0; i < 2; i++)
#pragma unroll
    for (int j = 0; j < 2; j++) acc[i][j] = (f32x16)(0.f);

  char* s0 = &lds[0][0]; char* s1 = &lds[1][0]; char* s2 = &lds[2][0];

  STG(s0, 0);
  STG(s1, 1);
  ENDW(4);

  // K = 1024 -> 32 K-steps: 30 main bodies + 2 tail
#pragma unroll 1
  for (int g = 0; g < 10; g++) {
    int t = 3 * g;
    BODY(s0, s2, t + 2);
    BODY(s1, s0, t + 3);
    BODY(s2, s1, t + 4);
  }
  BODY_N0(s0);   // t = 30
  BODY_LAST(s1); // t = 31

  // epilogue: C/D layout col=lane&31, row=(r&3)+8*(r>>2)+4*half
  int colv[2]; float biasv[2];
#pragma unroll
  for (int nj = 0; nj < 2; nj++) {
    colv[nj] = n0 + wn + nj * 32 + l31;
    biasv[nj] = b1[e * D_FF + colv[nj]];
  }
#pragma unroll
  for (int mi = 0; mi < 2; mi++)
#pragma unroll
    for (int r = 0; r < 16; r++) {
      size_t row = (size_t)rowBase + wm + mi * 32 + (r & 3) + 8 * (r >> 2) + 4 * half;
#pragma unroll
      for (int nj = 0; nj < 2; nj++)
        H[row * D_FF + colv[nj]] = (__bf16)gelu_fast(acc[mi][nj][r] + biasv[nj]);
    }
}

// ---------------- GEMM2: out[t] += w * (H @ W2[e] + b2[e])  (fused combine) ----
// grid 1D = 17*64; same XCD swizzle (8 nb-blocks of an mt-group on one XCD).
__global__ __launch_bounds__(256, 3) void k_gemm2(
    const __bf16* __restrict__ H, const __bf16* __restrict__ W2T,
    const float* __restrict__ b2, float* __restrict__ out,
    const int* __restrict__ row2pair, const float* __restrict__ pairW,
    const int* __restrict__ t2e, const int* __restrict__ trow) {
  __shared__ __align__(16) char lds[3][16384];
  const int bid = blockIdx.x;
  const int q = bid >> 6, w8 = bid & 63;
  const int nb = w8 >> 3, mt = q * 8 + (w8 & 7);
  const int e = t2e[mt];
  if (e < 0) return;
  const int rowBase = trow[mt];
  const int n0 = nb * 128;

  const int tid = threadIdx.x;
  const int l = tid & 63, w = tid >> 6;
  const int wm = (w >> 1) * 64, wn = (w & 1) * 64;
  const int l31 = l & 31, half = l >> 5;
  const int rsub = l >> 2;
  const int sg = (l & 3) ^ ((l >> 3) & 3);
  const int aoff = ((half ^ ((l >> 1) & 3)) << 4);

  const char* srcA0 = (const char*)(H + (size_t)(rowBase + 16 * w + rsub) * D_FF) + sg * 16;
  const char* srcA1 = srcA0 + (size_t)64 * D_FF * 2;
  const __bf16* Bb = W2T + (size_t)e * D_MODEL * D_FF + (size_t)n0 * D_FF;
  const char* srcB0 = (const char*)(Bb + (size_t)(16 * w + rsub) * D_FF) + sg * 16;
  const char* srcB1 = srcB0 + (size_t)64 * D_FF * 2;

  f32x16 acc[2][2];
#pragma unroll
  for (int i = 0; i < 2; i++)
#pragma unroll
    for (int j = 0; j < 2; j++) acc[i][j] = (f32x16)(0.f);

  char* s0 = &lds[0][0]; char* s1 = &lds[1][0]; char* s2 = &lds[2][0];

  STG(s0, 0);
  STG(s1, 1);
  ENDW(4);

  // K = 4096 -> 128 K-steps: 126 main bodies + 2 tail
#pragma unroll 1
  for (int g = 0; g < 42; g++) {
    int t = 3 * g;
    BODY(s0, s2, t + 2);
    BODY(s1, s0, t + 3);
    BODY(s2, s1, t + 4);
  }
  BODY_N0(s0);   // t = 126
  BODY_LAST(s1); // t = 127

  // epilogue: fused combine — 2 commutative fp32 atomic adds per element
  int colv[2]; float biasv[2];
#pragma unroll
  for (int nj = 0; nj < 2; nj++) {
    colv[nj] = n0 + wn + nj * 32 + l31;
    biasv[nj] = b2[e * D_MODEL + colv[nj]];
  }
#pragma unroll
  for (int mi = 0; mi < 2; mi++)
#pragma unroll
    for (int r = 0; r < 16; r++) {
      int row = rowBase + wm + mi * 32 + (r & 3) + 8 * (r >> 2) + 4 * half;
      int pair = row2pair[row];
      if (pair < 0) continue;
      float pw = pairW[pair];
      size_t tok = (size_t)(pair >> 1);
#pragma unroll
      for (int nj = 0; nj < 2; nj++)
        atomicAdd(out + tok * D_MODEL + colv[nj], pw * (acc[mi][nj][r] + biasv[nj]));
    }
}

extern "C" void kernel_launch(void* const* d_in, const int* in_sizes, int n_in,
                              void* d_out, int out_size, void* d_ws, size_t ws_size,
                              hipStream_t stream) {
  const float* x  = (const float*)d_in[0];
  const float* Wg = (const float*)d_in[1];
  const float* bg = (const float*)d_in[2];
  const float* W1 = (const float*)d_in[3];
  const float* b1 = (const float*)d_in[4];
  const float* W2 = (const float*)d_in[5];
  const float* b2 = (const float*)d_in[6];
  float* out        = (float*)d_out;
  float* logits_out = out + (size_t)T_TOK * D_MODEL;

  char* ws = (char*)d_ws;
  __bf16* W1T = (__bf16*)(ws + OFF_W1T);
  __bf16* W2T = (__bf16*)(ws + OFF_W2T);
  __bf16* H   = (__bf16*)(ws + OFF_H);
  __bf16* XR  = (__bf16*)(ws + OFF_XR);
  char* meta = ws + OFF_META;
  int*   pairExpert = (int*)(meta + M_PAIREXP);
  float* pairW      = (float*)(meta + M_PAIRW);
  int*   row2pair   = (int*)(meta + M_ROW2P);
  int*   counts     = (int*)(meta + M_COUNTS);
  int*   padStart   = (int*)(meta + M_PADST);
  int*   cursor     = (int*)(meta + M_CURSOR);
  int*   t2e        = (int*)(meta + M_T2E);
  int*   trow       = (int*)(meta + M_TROW);

  // zero the combined output (gemm2 accumulates into it atomically)
  hipMemsetAsync(out, 0, (size_t)T_TOK * D_MODEL * sizeof(float), stream);

  k_convT<<<dim3(D_FF / 64, D_MODEL / 64, N_EXP), 256, 0, stream>>>(W1, W1T, D_MODEL, D_FF);
  k_convT<<<dim3(D_MODEL / 64, D_FF / 64, N_EXP), 256, 0, stream>>>(W2, W2T, D_FF, D_MODEL);

  k_init<<<(CAP_ROWS + 255) / 256, 256, 0, stream>>>(row2pair);
  k_gate<<<T_TOK / 4, 256, 0, stream>>>(x, Wg, bg, logits_out, pairExpert, pairW);
  k_offsets<<<1, 256, 0, stream>>>(pairExpert, counts, padStart, cursor, t2e, trow);
  k_place<<<NPAIR / 256, 256, 0, stream>>>(pairExpert, padStart, cursor, row2pair);
  k_gather<<<CAP_ROWS, 256, 0, stream>>>(x, row2pair, XR);

  k_gemm1<<<(MAX_TILES / 8) * 256, 256, 0, stream>>>(XR, W1T, b1, H, t2e, trow);
  k_gemm2<<<(MAX_TILES / 8) * 64, 256, 0, stream>>>(H, W2T, b2, out, row2pair, pairW, t2e, trow);
}